// Round 1
// baseline (125.294 us; speedup 1.0000x reference)
//
#include <hip/hip_runtime.h>

typedef __attribute__((ext_vector_type(8))) short short8;
typedef __attribute__((ext_vector_type(4))) float f32x4;

#define S_LEN 1024
#define B_N 8
#define D_DIM 512
#define SLAB 4194304  // 8192*512 elements per tfm slab

static __device__ __forceinline__ unsigned short f2bf(float f){
  unsigned int u = __float_as_uint(f);
  u = u + 0x7fffu + ((u>>16)&1u);
  return (unsigned short)(u>>16);
}
static __device__ __forceinline__ float bf2f(unsigned short h){
  return __uint_as_float(((unsigned int)h)<<16);
}

#define GLL16(g,l) __builtin_amdgcn_global_load_lds( \
    (__attribute__((address_space(1))) void*)(g), \
    (__attribute__((address_space(3))) void*)(l), 16, 0, 0)

// ---------------- convert x -> bf16, compute row inverse norms ----------------
__global__ __launch_bounds__(256) void k_conv_x(const float* __restrict__ x,
    unsigned short* __restrict__ xbf, float* __restrict__ invn)
{
  int row = blockIdx.x, tid = threadIdx.x;
  size_t off = (size_t)row*D_DIM + tid*2;
  float2 v = *(const float2*)(x + off);
  ushort2 h; h.x = f2bf(v.x); h.y = f2bf(v.y);
  *(ushort2*)(xbf + off) = h;
  float ss = v.x*v.x + v.y*v.y;
  for (int o=32;o;o>>=1) ss += __shfl_down(ss,o,64);
  __shared__ float red[4];
  if ((tid&63)==0) red[tid>>6] = ss;
  __syncthreads();
  if (tid==0) invn[row] = 1.0f/fmaxf(sqrtf(red[0]+red[1]+red[2]+red[3]), 1e-12f);
}

// ---------------- convert W -> bf16 ----------------
__global__ __launch_bounds__(256) void k_conv_w(const float* __restrict__ Wsrc,
    unsigned short* __restrict__ wbf)
{
  int i = (blockIdx.x*256 + threadIdx.x)*4;
  float4 v = *(const float4*)(Wsrc + i);
  ushort4 h;
  h.x = f2bf(v.x); h.y = f2bf(v.y); h.z = f2bf(v.z); h.w = f2bf(v.w);
  *(ushort4*)(wbf + i) = h;
}

// ---------------- GEMM: C[m][row][j] = A[row,:]·W[m][j,:] + bias[m][j] (bf16 out) ----
// A: 8192x512 bf16 row-major; Bw: 1536x512 bf16 row-major (W flattened = B^T form)
// tile 128x128, BK=32, 4 waves (2x2), mfma 16x16x32 bf16
__global__ __launch_bounds__(256) void k_gemm(const unsigned short* __restrict__ A,
    const unsigned short* __restrict__ Bw, const float* __restrict__ bias,
    unsigned short* __restrict__ C)
{
  __shared__ __align__(16) unsigned short smem[16384]; // 32KB: As/Bs (16KB) alias Ct(32KB)
  unsigned short* As = smem;          // [128][32]
  unsigned short* Bs = smem + 4096;   // [128][32]
  int bx = blockIdx.x % 12, by = blockIdx.x / 12;
  int tid = threadIdx.x, lane = tid & 63, w = tid >> 6;
  int wm = w >> 1, wn = w & 1;
  // staging: chunk c (16B) -> row=c>>2, k8=(c&3)*8 ; wave-uniform LDS dest
  int c0 = w*128 + lane, c1 = c0 + 64;
  const unsigned short* gA0 = A + (size_t)(by*128 + (c0>>2))*512 + (c0&3)*8;
  const unsigned short* gA1 = A + (size_t)(by*128 + (c1>>2))*512 + (c1&3)*8;
  const unsigned short* gB0 = Bw + (size_t)(bx*128 + (c0>>2))*512 + (c0&3)*8;
  const unsigned short* gB1 = Bw + (size_t)(bx*128 + (c1>>2))*512 + (c1&3)*8;
  unsigned short* lA0 = As + (w*2+0)*512;
  unsigned short* lA1 = As + (w*2+1)*512;
  unsigned short* lB0 = Bs + (w*2+0)*512;
  unsigned short* lB1 = Bs + (w*2+1)*512;
  f32x4 acc[4][4];
  #pragma unroll
  for (int i=0;i<4;++i)
    #pragma unroll
    for (int j=0;j<4;++j)
      acc[i][j] = (f32x4){0.f,0.f,0.f,0.f};
  int lane15 = lane & 15, klo = (lane>>4)*8;
  for (int kt=0; kt<16; ++kt){
    GLL16(gA0, lA0); GLL16(gA1, lA1); GLL16(gB0, lB0); GLL16(gB1, lB1);
    gA0 += 32; gA1 += 32; gB0 += 32; gB1 += 32;
    __syncthreads();
    short8 af[4], bfr[4];
    #pragma unroll
    for (int i=0;i<4;++i)
      af[i] = *(const short8*)(As + (wm*64 + i*16 + lane15)*32 + klo);
    #pragma unroll
    for (int j=0;j<4;++j)
      bfr[j] = *(const short8*)(Bs + (wn*64 + j*16 + lane15)*32 + klo);
    #pragma unroll
    for (int i=0;i<4;++i)
      #pragma unroll
      for (int j=0;j<4;++j)
        acc[i][j] = __builtin_amdgcn_mfma_f32_16x16x32_bf16(af[i], bfr[j], acc[i][j], 0,0,0);
    __syncthreads();
  }
  // epilogue phase 1: acc + bias -> bf16 into LDS Ct[128][128]
  int rbase = (lane>>4)*4;
  #pragma unroll
  for (int j=0;j<4;++j){
    int nl = wn*64 + j*16 + lane15;
    float bv = bias[bx*128 + nl];
    #pragma unroll
    for (int i=0;i<4;++i){
      int rl0 = wm*64 + i*16 + rbase;
      #pragma unroll
      for (int rg=0;rg<4;++rg)
        smem[(rl0+rg)*128 + nl] = f2bf(acc[i][j][rg] + bv);
    }
  }
  __syncthreads();
  // epilogue phase 2: coalesced 16B stores
  int m_r = bx >> 2, colb = (bx&3)*128;
  #pragma unroll
  for (int p=0;p<8;++p){
    int R = p*16 + (tid>>4);
    int ch = (tid&15)*8;
    uint4 v = *(const uint4*)(smem + R*128 + ch);
    *(uint4*)(C + (size_t)m_r*SLAB + (size_t)(by*128 + R)*512 + colb + ch) = v;
  }
}

// ---------------- fused weights + stencil output ----------------
// one block per (b,t); b = blk&7 so each XCD gets one b with ascending t (L2 reuse)
__global__ __launch_bounds__(256) void k_stencil(const float* __restrict__ x,
    const unsigned short* __restrict__ tfm, const float* __restrict__ invn,
    const float* __restrict__ alphas, const float* __restrict__ betas,
    float* __restrict__ out)
{
  int blk = blockIdx.x;
  int b = blk & 7, t = blk >> 3;
  int tid = threadIdx.x, lane = tid & 63, wid = tid >> 6;
  __shared__ float cen[3][512];
  __shared__ float red[12];
  __shared__ float invc[3];
  __shared__ float wts[33];
  int d0 = tid*2;
  // windowed sums for the 3 radii (nested)
  float s3x=0,s3y=0,s5x=0,s5y=0,s7x=0,s7y=0;
  #pragma unroll
  for (int dl=-7; dl<=7; ++dl){
    int u = t + dl;
    if (u < 0 || u >= S_LEN) continue;
    float2 v = *(const float2*)(x + (size_t)(u*B_N+b)*D_DIM + d0);
    s7x+=v.x; s7y+=v.y;
    int a = dl<0 ? -dl : dl;
    if (a<=5){ s5x+=v.x; s5y+=v.y; }
    if (a<=3){ s3x+=v.x; s3y+=v.y; }
  }
  float cnt3 = (float)(min(t+4,S_LEN)-max(t-3,0));
  float cnt5 = (float)(min(t+6,S_LEN)-max(t-5,0));
  float cnt7 = (float)(min(t+8,S_LEN)-max(t-7,0));
  float c0x=s3x/cnt3, c0y=s3y/cnt3;
  float c1x=s5x/cnt5, c1y=s5y/cnt5;
  float c2x=s7x/cnt7, c2y=s7y/cnt7;
  cen[0][d0]=c0x; cen[0][d0+1]=c0y;
  cen[1][d0]=c1x; cen[1][d0+1]=c1y;
  cen[2][d0]=c2x; cen[2][d0+1]=c2y;
  float p0=c0x*c0x+c0y*c0y, p1=c1x*c1x+c1y*c1y, p2=c2x*c2x+c2y*c2y;
  for (int o=32;o;o>>=1){
    p0 += __shfl_down(p0,o,64);
    p1 += __shfl_down(p1,o,64);
    p2 += __shfl_down(p2,o,64);
  }
  if (lane==0){ red[wid]=p0; red[4+wid]=p1; red[8+wid]=p2; }
  __syncthreads();
  if (tid<3){
    float s = red[tid*4+0]+red[tid*4+1]+red[tid*4+2]+red[tid*4+3];
    invc[tid] = 1.0f/fmaxf(sqrtf(s), 1e-12f);
  }
  __syncthreads();
  // 33 similarity dots, distributed across 4 waves
  for (int p=wid; p<33; p+=4){
    int m, r, w;
    if (p<7){ m=0; r=3; w=p; } else if (p<18){ m=1; r=5; w=p-7; } else { m=2; r=7; w=p-18; }
    int pos = t + w - r;
    if (pos>=0 && pos<S_LEN){
      const float* xr = x + (size_t)(pos*B_N+b)*D_DIM + lane*8;
      const float* cr = &cen[m][lane*8];
      float4 a0 = *(const float4*)xr;
      float4 a1 = *(const float4*)(xr+4);
      float4 q0 = *(const float4*)cr;
      float4 q1 = *(const float4*)(cr+4);
      float dp = a0.x*q0.x + a0.y*q0.y + a0.z*q0.z + a0.w*q0.w
               + a1.x*q1.x + a1.y*q1.y + a1.z*q1.z + a1.w*q1.w;
      for (int o=32;o;o>>=1) dp += __shfl_down(dp,o,64);
      if (lane==0){
        float sim = dp * invn[pos*B_N+b] * invc[m];
        float z = alphas[m]*sim + betas[m];
        wts[p] = 1.0f/(1.0f+expf(-z));
      }
    } else if (lane==0) wts[p] = 0.0f;
  }
  __syncthreads();
  // gather: out = x + sum wts * tfm[pos]
  size_t xoff = (size_t)(t*B_N+b)*D_DIM + d0;
  float2 a = *(const float2*)(x + xoff);
  float accx = a.x, accy = a.y;
  #pragma unroll
  for (int p=0;p<33;++p){
    int m, r, w;
    if (p<7){ m=0; r=3; w=p; } else if (p<18){ m=1; r=5; w=p-7; } else { m=2; r=7; w=p-18; }
    int pos = t + w - r;
    if (pos<0 || pos>=S_LEN) continue;
    float wt = wts[p];
    const unsigned short* tp = tfm + (size_t)m*SLAB + (size_t)(pos*B_N+b)*D_DIM + d0;
    unsigned int uv = *(const unsigned int*)tp;
    accx += wt * bf2f((unsigned short)(uv & 0xffffu));
    accy += wt * bf2f((unsigned short)(uv >> 16));
  }
  *(float2*)(out + xoff) = make_float2(accx, accy);
}

extern "C" void kernel_launch(void* const* d_in, const int* in_sizes, int n_in,
                              void* d_out, int out_size, void* d_ws, size_t ws_size,
                              hipStream_t stream) {
  const float* x      = (const float*)d_in[0];
  const float* W      = (const float*)d_in[1];
  const float* bias   = (const float*)d_in[2];
  const float* alphas = (const float*)d_in[3];
  const float* betas  = (const float*)d_in[4];
  float* out = (float*)d_out;
  char* ws = (char*)d_ws;
  unsigned short* xbf  = (unsigned short*)ws;                               // 8,388,608 B
  unsigned short* wbf  = (unsigned short*)(ws + 8388608);                   // 1,572,864 B
  float*          invn = (float*)(ws + 8388608 + 1572864);                  //    32,768 B
  unsigned short* tfm  = (unsigned short*)(ws + 8388608 + 1572864 + 32768); // 25,165,824 B

  k_conv_x<<<8192, 256, 0, stream>>>(x, xbf, invn);
  k_conv_w<<<768, 256, 0, stream>>>(W, wbf);
  k_gemm<<<768, 256, 0, stream>>>(xbf, wbf, bias, tfm);
  k_stencil<<<8192, 256, 0, stream>>>(x, tfm, invn, alphas, betas, out);
}

// Round 3
// 73.484 us; speedup vs baseline: 1.7051x; 1.7051x over previous
//
#include <hip/hip_runtime.h>

typedef __attribute__((ext_vector_type(8))) short short8;
typedef __attribute__((ext_vector_type(4))) float f32x4;

#define S_LEN 1024
#define B_N 8
#define D_DIM 512
#define SLAB 4194304  // 8192*512 elements per tfm slab

static __device__ __forceinline__ unsigned short f2bf(float f){
  unsigned int u = __float_as_uint(f);
  u = u + 0x7fffu + ((u>>16)&1u);
  return (unsigned short)(u>>16);
}
static __device__ __forceinline__ float bf2f(unsigned short h){
  return __uint_as_float(((unsigned int)h)<<16);
}

#define GLL16(g,l) __builtin_amdgcn_global_load_lds( \
    (__attribute__((address_space(1))) void*)(g), \
    (__attribute__((address_space(3))) void*)(l), 16, 0, 0)

// ---------------- convert x -> bf16, compute row inverse norms ----------------
__global__ __launch_bounds__(256) void k_conv_x(const float* __restrict__ x,
    unsigned short* __restrict__ xbf, float* __restrict__ invn)
{
  int row = blockIdx.x, tid = threadIdx.x;
  size_t off = (size_t)row*D_DIM + tid*2;
  float2 v = *(const float2*)(x + off);
  ushort2 h; h.x = f2bf(v.x); h.y = f2bf(v.y);
  *(ushort2*)(xbf + off) = h;
  float ss = v.x*v.x + v.y*v.y;
  for (int o=32;o;o>>=1) ss += __shfl_down(ss,o,64);
  __shared__ float red[4];
  if ((tid&63)==0) red[tid>>6] = ss;
  __syncthreads();
  if (tid==0) invn[row] = 1.0f/fmaxf(sqrtf(red[0]+red[1]+red[2]+red[3]), 1e-12f);
}

// ---------------- convert W -> bf16 ----------------
__global__ __launch_bounds__(256) void k_conv_w(const float* __restrict__ Wsrc,
    unsigned short* __restrict__ wbf)
{
  int i = (blockIdx.x*256 + threadIdx.x)*4;
  float4 v = *(const float4*)(Wsrc + i);
  ushort4 h;
  h.x = f2bf(v.x); h.y = f2bf(v.y); h.z = f2bf(v.z); h.w = f2bf(v.w);
  *(ushort4*)(wbf + i) = h;
}

// ---------------- GEMM: C[m][row][j] = A[row,:]·W[m][j,:] + bias[m][j] (bf16 out) ----
__global__ __launch_bounds__(256) void k_gemm(const unsigned short* __restrict__ A,
    const unsigned short* __restrict__ Bw, const float* __restrict__ bias,
    unsigned short* __restrict__ C)
{
  __shared__ __align__(16) unsigned short smem[16384]; // 32KB: As/Bs (16KB) alias Ct(32KB)
  unsigned short* As = smem;          // [128][32]
  unsigned short* Bs = smem + 4096;   // [128][32]
  int bx = blockIdx.x % 12, by = blockIdx.x / 12;
  int tid = threadIdx.x, lane = tid & 63, w = tid >> 6;
  int wm = w >> 1, wn = w & 1;
  int c0 = w*128 + lane, c1 = c0 + 64;
  const unsigned short* gA0 = A + (size_t)(by*128 + (c0>>2))*512 + (c0&3)*8;
  const unsigned short* gA1 = A + (size_t)(by*128 + (c1>>2))*512 + (c1&3)*8;
  const unsigned short* gB0 = Bw + (size_t)(bx*128 + (c0>>2))*512 + (c0&3)*8;
  const unsigned short* gB1 = Bw + (size_t)(bx*128 + (c1>>2))*512 + (c1&3)*8;
  unsigned short* lA0 = As + (w*2+0)*512;
  unsigned short* lA1 = As + (w*2+1)*512;
  unsigned short* lB0 = Bs + (w*2+0)*512;
  unsigned short* lB1 = Bs + (w*2+1)*512;
  f32x4 acc[4][4];
  #pragma unroll
  for (int i=0;i<4;++i)
    #pragma unroll
    for (int j=0;j<4;++j)
      acc[i][j] = (f32x4){0.f,0.f,0.f,0.f};
  int lane15 = lane & 15, klo = (lane>>4)*8;
  for (int kt=0; kt<16; ++kt){
    GLL16(gA0, lA0); GLL16(gA1, lA1); GLL16(gB0, lB0); GLL16(gB1, lB1);
    gA0 += 32; gA1 += 32; gB0 += 32; gB1 += 32;
    __syncthreads();
    short8 af[4], bfr[4];
    #pragma unroll
    for (int i=0;i<4;++i)
      af[i] = *(const short8*)(As + (wm*64 + i*16 + lane15)*32 + klo);
    #pragma unroll
    for (int j=0;j<4;++j)
      bfr[j] = *(const short8*)(Bs + (wn*64 + j*16 + lane15)*32 + klo);
    #pragma unroll
    for (int i=0;i<4;++i)
      #pragma unroll
      for (int j=0;j<4;++j)
        acc[i][j] = __builtin_amdgcn_mfma_f32_16x16x32_bf16(af[i], bfr[j], acc[i][j], 0,0,0);
    __syncthreads();
  }
  int rbase = (lane>>4)*4;
  #pragma unroll
  for (int j=0;j<4;++j){
    int nl = wn*64 + j*16 + lane15;
    float bv = bias[bx*128 + nl];
    #pragma unroll
    for (int i=0;i<4;++i){
      int rl0 = wm*64 + i*16 + rbase;
      #pragma unroll
      for (int rg=0;rg<4;++rg)
        smem[(rl0+rg)*128 + nl] = f2bf(acc[i][j][rg] + bv);
    }
  }
  __syncthreads();
  int m_r = bx >> 2, colb = (bx&3)*128;
  #pragma unroll
  for (int p=0;p<8;++p){
    int R = p*16 + (tid>>4);
    int ch = (tid&15)*8;
    uint4 v = *(const uint4*)(smem + R*128 + ch);
    *(uint4*)(C + (size_t)m_r*SLAB + (size_t)(by*128 + R)*512 + colb + ch) = v;
  }
}

// ---------------- banded Gram: Gband[b][i][dl+14] = x[b,i]·x[b,i+dl], |dl|<=14 ----
// grid 512 = 8 b x 64 i0-blocks; 3 waves: j0 = i0 + (w-1)*16
__global__ __launch_bounds__(192) void k_gram(const unsigned short* __restrict__ xbf,
    float* __restrict__ Gband)
{
  int blk = blockIdx.x;
  int b = blk & 7, i0 = (blk >> 3) * 16;
  int tid = threadIdx.x, lane = tid & 63, w = tid >> 6;
  int j0 = i0 + (w - 1) * 16;
  if (j0 < 0 || j0 >= S_LEN) return;
  int l15 = lane & 15, klo = (lane >> 4) * 8;
  const unsigned short* Ar = xbf + ((size_t)(i0 + l15) * B_N + b) * D_DIM + klo;
  const unsigned short* Br = xbf + ((size_t)(j0 + l15) * B_N + b) * D_DIM + klo;
  f32x4 acc = (f32x4){0.f,0.f,0.f,0.f};
  #pragma unroll
  for (int kt = 0; kt < 16; ++kt){
    short8 af = *(const short8*)(Ar + kt*32);
    short8 bf = *(const short8*)(Br + kt*32);
    acc = __builtin_amdgcn_mfma_f32_16x16x32_bf16(af, bf, acc, 0,0,0);
  }
  int rb = (lane >> 4) * 4;
  #pragma unroll
  for (int rg = 0; rg < 4; ++rg){
    int i = i0 + rb + rg;
    int j = j0 + l15;
    int dl = j - i;
    if (dl >= -14 && dl <= 14)
      Gband[((size_t)b * S_LEN + i) * 32 + dl + 14] = acc[rg];
  }
}

// ---------------- weights: one wave per (b,t), lane = window slot ----------------
// sim(pos; t,m) = (x[pos]·sum_win) / (||x[pos]|| * ||sum_win||)   [cnt cancels]
__global__ __launch_bounds__(256) void k_wts(const float* __restrict__ Gband,
    const float* __restrict__ invn, const float* __restrict__ alphas,
    const float* __restrict__ betas, float* __restrict__ wts)
{
  int blk = blockIdx.x;           // 2048 = 8 b x 256 tg
  int b = blk & 7, tg = blk >> 3;
  int tid = threadIdx.x, lane = tid & 63, wid = tid >> 6;
  int t = tg * 4 + wid;
  __shared__ float pshare[4][33];
  __shared__ float invc[4][3];
  int p = lane;
  float pp = 0.f; int m = 0, pos = 0, valid = 0;
  if (p < 33){
    int r, wsl;
    if (p < 7){ m = 0; r = 3; wsl = p; }
    else if (p < 18){ m = 1; r = 5; wsl = p - 7; }
    else { m = 2; r = 7; wsl = p - 18; }
    pos = t + wsl - r;
    valid = (pos >= 0 && pos < S_LEN);
    if (valid){
      int ulo = max(t - r, 0), uhi = min(t + r, S_LEN - 1);
      size_t base = ((size_t)b * S_LEN + pos) * 32;
      for (int u = ulo; u <= uhi; ++u)
        pp += Gband[base + (u - pos + 14)];
    }
    pshare[wid][p] = valid ? pp : 0.f;
  }
  __syncthreads();
  if (lane < 3){
    int s0 = lane == 0 ? 0 : (lane == 1 ? 7 : 18);
    int c  = lane == 0 ? 7 : (lane == 1 ? 11 : 15);
    float s = 0.f;
    for (int k = 0; k < c; ++k) s += pshare[wid][s0 + k];
    invc[wid][lane] = 1.0f / fmaxf(sqrtf(s), 1e-12f);
  }
  __syncthreads();
  if (p < 33){
    float wt = 0.f;
    if (valid){
      float sim = pp * invn[pos * B_N + b] * invc[wid][m];
      float z = alphas[m] * sim + betas[m];
      wt = 1.0f / (1.0f + expf(-z));
    }
    wts[((size_t)t * B_N + b) * 33 + p] = wt;
  }
}

// ---------------- gather: out = x + sum_p wts[p] * tfm[m_p][pos_p] ----------------
// block 256 = 2 halves x 128 threads; half handles one (b,t), 4 floats/thread
__global__ __launch_bounds__(256) void k_gath(const float* __restrict__ x,
    const unsigned short* __restrict__ tfm, const float* __restrict__ wts,
    float* __restrict__ out)
{
  int blk = blockIdx.x;           // 4096 = 8 b x 512 tg
  int b = blk & 7, tg = blk >> 3;
  int tid = threadIdx.x, h = tid >> 7, j = tid & 127;
  int t = tg * 2 + h;
  __shared__ float wsh[2][33];
  if (j < 33) wsh[h][j] = wts[((size_t)t * B_N + b) * 33 + j];
  __syncthreads();
  int d0 = j * 4;
  size_t xoff = ((size_t)t * B_N + b) * D_DIM + d0;
  float4 a = *(const float4*)(x + xoff);
  float ax = a.x, ay = a.y, az = a.z, aw = a.w;
  #pragma unroll
  for (int p = 0; p < 33; ++p){
    int m, r, wsl;
    if (p < 7){ m = 0; r = 3; wsl = p; }
    else if (p < 18){ m = 1; r = 5; wsl = p - 7; }
    else { m = 2; r = 7; wsl = p - 18; }
    int pos = t + wsl - r;
    if (pos < 0 || pos >= S_LEN) continue;
    float wt = wsh[h][p];
    const unsigned short* tp = tfm + (size_t)m * SLAB + ((size_t)pos * B_N + b) * D_DIM + d0;
    uint2 uv = *(const uint2*)tp;
    ax += wt * bf2f((unsigned short)(uv.x & 0xffffu));
    ay += wt * bf2f((unsigned short)(uv.x >> 16));
    az += wt * bf2f((unsigned short)(uv.y & 0xffffu));
    aw += wt * bf2f((unsigned short)(uv.y >> 16));
  }
  *(float4*)(out + xoff) = make_float4(ax, ay, az, aw);
}

extern "C" void kernel_launch(void* const* d_in, const int* in_sizes, int n_in,
                              void* d_out, int out_size, void* d_ws, size_t ws_size,
                              hipStream_t stream) {
  const float* x      = (const float*)d_in[0];
  const float* W      = (const float*)d_in[1];
  const float* bias   = (const float*)d_in[2];
  const float* alphas = (const float*)d_in[3];
  const float* betas  = (const float*)d_in[4];
  float* out = (float*)d_out;
  char* ws = (char*)d_ws;
  unsigned short* xbf  = (unsigned short*)ws;                               // 8,388,608 B
  unsigned short* wbf  = (unsigned short*)(ws + 8388608);                   // 1,572,864 B
  float*          invn = (float*)(ws + 8388608 + 1572864);                  //    32,768 B
  unsigned short* tfm  = (unsigned short*)(ws + 8388608 + 1572864 + 32768); // 25,165,824 B
  float*          Gband= (float*)(ws + 8388608 + 1572864 + 32768 + 25165824);      // 1,048,576 B
  float*          wts  = (float*)(ws + 8388608 + 1572864 + 32768 + 25165824 + 1048576); // 1,081,344 B

  k_conv_x<<<8192, 256, 0, stream>>>(x, xbf, invn);
  k_conv_w<<<768, 256, 0, stream>>>(W, wbf);
  k_gram<<<512, 192, 0, stream>>>(xbf, Gband);
  k_gemm<<<768, 256, 0, stream>>>(xbf, wbf, bias, tfm);
  k_wts<<<2048, 256, 0, stream>>>(Gband, invn, alphas, betas, wts);
  k_gath<<<4096, 256, 0, stream>>>(x, tfm, wts, out);
}

// Round 4
// 67.808 us; speedup vs baseline: 1.8478x; 1.0837x over previous
//
#include <hip/hip_runtime.h>

typedef __attribute__((ext_vector_type(8))) short short8;
typedef __attribute__((ext_vector_type(4))) float f32x4;

#define S_LEN 1024
#define B_N 8
#define D_DIM 512
#define SLAB 4194304    // 8192*512 elements per tfm slab
#define NX   4194304    // x element count
#define NW   786432     // W element count

static __device__ __forceinline__ unsigned short f2bf(float f){
  unsigned int u = __float_as_uint(f);
  u = u + 0x7fffu + ((u>>16)&1u);
  return (unsigned short)(u>>16);
}
static __device__ __forceinline__ float bf2f(unsigned short h){
  return __uint_as_float(((unsigned int)h)<<16);
}

#define GLL16(g,l) __builtin_amdgcn_global_load_lds( \
    (__attribute__((address_space(1))) void*)(g), \
    (__attribute__((address_space(3))) void*)(l), 16, 0, 0)

// ---------------- fused convert: x and W -> bf16 (pure cast stream) ----------------
__global__ __launch_bounds__(256) void k_conv(const float* __restrict__ x,
    const float* __restrict__ W, unsigned short* __restrict__ xbf,
    unsigned short* __restrict__ wbf)
{
  size_t i = ((size_t)blockIdx.x*256 + threadIdx.x)*4;
  const float* src; unsigned short* dst;
  if (i < NX){ src = x + i; dst = xbf + i; }
  else       { src = W + (i - NX); dst = wbf + (i - NX); }
  float4 v = *(const float4*)src;
  ushort4 h;
  h.x = f2bf(v.x); h.y = f2bf(v.y); h.z = f2bf(v.z); h.w = f2bf(v.w);
  *(ushort4*)dst = h;
}

// ---------------- heavy: gemm blocks [0,768) + gram blocks [768,1280) ----------------
// gemm: C[m][row][j] = A[row,:]·W[m][j,:] + bias[m][j], tile 128x128 BK=32, 4 waves
// gram: Gband[b][i][dl+14] = x[b,i]·x[b,i+dl], |dl|<=14, via 16x16x32 MFMA
__global__ __launch_bounds__(256) void k_heavy(const unsigned short* __restrict__ A,
    const unsigned short* __restrict__ Bw, const float* __restrict__ bias,
    unsigned short* __restrict__ C, float* __restrict__ Gband)
{
  __shared__ __align__(16) unsigned short smem[16384]; // 32KB: As/Bs alias Ct
  int blk = blockIdx.x;
  int tid = threadIdx.x, lane = tid & 63, w = tid >> 6;

  if (blk >= 768){
    // ---- gram path ----
    if (w >= 3) return;
    int g = blk - 768;
    int b = g & 7, i0 = (g >> 3) * 16;
    int j0 = i0 + (w - 1) * 16;
    if (j0 < 0 || j0 >= S_LEN) return;
    int l15 = lane & 15, klo = (lane >> 4) * 8;
    const unsigned short* Ar = A + ((size_t)(i0 + l15) * B_N + b) * D_DIM + klo;
    const unsigned short* Br = A + ((size_t)(j0 + l15) * B_N + b) * D_DIM + klo;
    f32x4 acc = (f32x4){0.f,0.f,0.f,0.f};
    #pragma unroll
    for (int kt = 0; kt < 16; ++kt){
      short8 af = *(const short8*)(Ar + kt*32);
      short8 bf = *(const short8*)(Br + kt*32);
      acc = __builtin_amdgcn_mfma_f32_16x16x32_bf16(af, bf, acc, 0,0,0);
    }
    int rb = (lane >> 4) * 4;
    #pragma unroll
    for (int rg = 0; rg < 4; ++rg){
      int i = i0 + rb + rg;
      int dl = j0 + l15 - i;
      if (dl >= -14 && dl <= 14)
        Gband[((size_t)b * S_LEN + i) * 32 + dl + 14] = acc[rg];
    }
    return;
  }

  // ---- gemm path ----
  unsigned short* As = smem;          // [128][32]
  unsigned short* Bs = smem + 4096;   // [128][32]
  int bx = blk % 12, by = blk / 12;
  int wm = w >> 1, wn = w & 1;
  int c0 = w*128 + lane, c1 = c0 + 64;
  const unsigned short* gA0 = A + (size_t)(by*128 + (c0>>2))*512 + (c0&3)*8;
  const unsigned short* gA1 = A + (size_t)(by*128 + (c1>>2))*512 + (c1&3)*8;
  const unsigned short* gB0 = Bw + (size_t)(bx*128 + (c0>>2))*512 + (c0&3)*8;
  const unsigned short* gB1 = Bw + (size_t)(bx*128 + (c1>>2))*512 + (c1&3)*8;
  unsigned short* lA0 = As + (w*2+0)*512;
  unsigned short* lA1 = As + (w*2+1)*512;
  unsigned short* lB0 = Bs + (w*2+0)*512;
  unsigned short* lB1 = Bs + (w*2+1)*512;
  f32x4 acc[4][4];
  #pragma unroll
  for (int i=0;i<4;++i)
    #pragma unroll
    for (int j=0;j<4;++j)
      acc[i][j] = (f32x4){0.f,0.f,0.f,0.f};
  int lane15 = lane & 15, klo = (lane>>4)*8;
  for (int kt=0; kt<16; ++kt){
    GLL16(gA0, lA0); GLL16(gA1, lA1); GLL16(gB0, lB0); GLL16(gB1, lB1);
    gA0 += 32; gA1 += 32; gB0 += 32; gB1 += 32;
    __syncthreads();
    short8 af[4], bfr[4];
    #pragma unroll
    for (int i=0;i<4;++i)
      af[i] = *(const short8*)(As + (wm*64 + i*16 + lane15)*32 + klo);
    #pragma unroll
    for (int j=0;j<4;++j)
      bfr[j] = *(const short8*)(Bs + (wn*64 + j*16 + lane15)*32 + klo);
    #pragma unroll
    for (int i=0;i<4;++i)
      #pragma unroll
      for (int j=0;j<4;++j)
        acc[i][j] = __builtin_amdgcn_mfma_f32_16x16x32_bf16(af[i], bfr[j], acc[i][j], 0,0,0);
    __syncthreads();
  }
  int rbase = (lane>>4)*4;
  #pragma unroll
  for (int j=0;j<4;++j){
    int nl = wn*64 + j*16 + lane15;
    float bv = bias[bx*128 + nl];
    #pragma unroll
    for (int i=0;i<4;++i){
      int rl0 = wm*64 + i*16 + rbase;
      #pragma unroll
      for (int rg=0;rg<4;++rg)
        smem[(rl0+rg)*128 + nl] = f2bf(acc[i][j][rg] + bv);
    }
  }
  __syncthreads();
  int m_r = bx >> 2, colb = (bx&3)*128;
  #pragma unroll
  for (int p=0;p<8;++p){
    int R = p*16 + (tid>>4);
    int ch = (tid&15)*8;
    uint4 v = *(const uint4*)(smem + R*128 + ch);
    *(uint4*)(C + (size_t)m_r*SLAB + (size_t)(by*128 + R)*512 + colb + ch) = v;
  }
}

// ---------------- fused weights + gather ----------------
// block 256 = 2 halves x 128 threads; half h handles (b, t=tg*2+h)
// sim(pos;t,m) = pp * rsqrt(G[pos][pos]) * rsqrt(sum_win pp)   [cnt cancels]
__global__ __launch_bounds__(256) void k_gath(const float* __restrict__ x,
    const unsigned short* __restrict__ tfm, const float* __restrict__ Gband,
    const float* __restrict__ alphas, const float* __restrict__ betas,
    float* __restrict__ out)
{
  int blk = blockIdx.x;           // 4096 = 8 b x 512 tg
  int b = blk & 7, tg = blk >> 3;
  int tid = threadIdx.x, h = tid >> 7, j = tid & 127;
  int t = tg * 2 + h;
  __shared__ float pshare[2][33];
  __shared__ float invc[2][3];
  __shared__ float wsh[2][33];
  int m = 0, pos = 0, valid = 0;
  float pp = 0.f, invnp = 0.f;
  if (j < 33){
    int r, wsl;
    if (j < 7){ m = 0; r = 3; wsl = j; }
    else if (j < 18){ m = 1; r = 5; wsl = j - 7; }
    else { m = 2; r = 7; wsl = j - 18; }
    pos = t + wsl - r;
    valid = (pos >= 0 && pos < S_LEN);
    if (valid){
      const float* grow = Gband + ((size_t)b * S_LEN + pos) * 32;
      int ulo = max(t - r, 0), uhi = min(t + r, S_LEN - 1);
      for (int u = ulo; u <= uhi; ++u) pp += grow[u - pos + 14];
      invnp = rsqrtf(fmaxf(grow[14], 1e-24f));
    }
    pshare[h][j] = valid ? pp : 0.f;
  }
  __syncthreads();
  if (j < 3){
    int s0 = j == 0 ? 0 : (j == 1 ? 7 : 18);
    int c  = j == 0 ? 7 : (j == 1 ? 11 : 15);
    float s = 0.f;
    for (int k = 0; k < c; ++k) s += pshare[h][s0 + k];
    invc[h][j] = rsqrtf(fmaxf(s, 1e-24f));
  }
  __syncthreads();
  if (j < 33){
    float wt = 0.f;
    if (valid){
      float sim = pp * invnp * invc[h][m];
      float z = alphas[m] * sim + betas[m];
      wt = 1.0f / (1.0f + expf(-z));
    }
    wsh[h][j] = wt;
  }
  __syncthreads();
  int d0 = j * 4;
  size_t xoff = ((size_t)t * B_N + b) * D_DIM + d0;
  float4 a = *(const float4*)(x + xoff);
  float ax = a.x, ay = a.y, az = a.z, aw = a.w;
  #pragma unroll
  for (int p = 0; p < 33; ++p){
    int pm, pr, wsl;
    if (p < 7){ pm = 0; pr = 3; wsl = p; }
    else if (p < 18){ pm = 1; pr = 5; wsl = p - 7; }
    else { pm = 2; pr = 7; wsl = p - 18; }
    int ppos = t + wsl - pr;
    if (ppos < 0 || ppos >= S_LEN) continue;
    float wt = wsh[h][p];
    const unsigned short* tp = tfm + (size_t)pm * SLAB + ((size_t)ppos * B_N + b) * D_DIM + d0;
    uint2 uv = *(const uint2*)tp;
    ax += wt * bf2f((unsigned short)(uv.x & 0xffffu));
    ay += wt * bf2f((unsigned short)(uv.x >> 16));
    az += wt * bf2f((unsigned short)(uv.y & 0xffffu));
    aw += wt * bf2f((unsigned short)(uv.y >> 16));
  }
  *(float4*)(out + xoff) = make_float4(ax, ay, az, aw);
}

extern "C" void kernel_launch(void* const* d_in, const int* in_sizes, int n_in,
                              void* d_out, int out_size, void* d_ws, size_t ws_size,
                              hipStream_t stream) {
  const float* x      = (const float*)d_in[0];
  const float* W      = (const float*)d_in[1];
  const float* bias   = (const float*)d_in[2];
  const float* alphas = (const float*)d_in[3];
  const float* betas  = (const float*)d_in[4];
  float* out = (float*)d_out;
  char* ws = (char*)d_ws;
  unsigned short* xbf  = (unsigned short*)ws;                               //  8,388,608 B
  unsigned short* wbf  = (unsigned short*)(ws + 8388608);                   //  1,572,864 B
  unsigned short* tfm  = (unsigned short*)(ws + 8388608 + 1572864);         // 25,165,824 B
  float*          Gband= (float*)(ws + 8388608 + 1572864 + 25165824);       //  1,048,576 B

  k_conv <<<4864, 256, 0, stream>>>(x, W, xbf, wbf);
  k_heavy<<<1280, 256, 0, stream>>>(xbf, wbf, bias, tfm, Gband);
  k_gath <<<4096, 256, 0, stream>>>(x, tfm, Gband, alphas, betas, out);
}